// Round 8
// baseline (2617.727 us; speedup 1.0000x reference)
//
#include <hip/hip_runtime.h>
#include <math.h>

#define NV 50000
#define NE 10000
#define NP 800000
#define CH 512      // HEADS * C_HID
#define NC 40
#define SLOPE 0.2f

// ---------- helpers ----------
__device__ __forceinline__ unsigned encf(float f){
  unsigned u = __float_as_uint(f);
  return (u>>31)? ~u : (u|0x80000000u);
}
__device__ __forceinline__ float decf(unsigned e){
  return (e&0x80000000u)? __uint_as_float(e&0x7FFFFFFFu) : __uint_as_float(~e);
}

// ---------- CSR build ----------
__global__ __launch_bounds__(256) void k_hist(const int* __restrict__ v_ids, const int* __restrict__ e_ids,
                                              int* __restrict__ cnt_e, int* __restrict__ cnt_v)
{
  int i = blockIdx.x*256 + threadIdx.x;
  if(i<NP){ atomicAdd(&cnt_e[e_ids[i]],1); atomicAdd(&cnt_v[v_ids[i]],1); }
}

__global__ __launch_bounds__(1024) void k_scan(const int* __restrict__ cnt, int n,
                                               int* __restrict__ off, int* __restrict__ cur)
{
  __shared__ int wsum[16];
  __shared__ int runs;
  int tid=threadIdx.x, lane=tid&63, wid=tid>>6;
  if(tid==0) runs=0;
  __syncthreads();
  for(int base=0;base<n;base+=1024){
    int i=base+tid;
    int x=(i<n)?cnt[i]:0;
    int incl=x;
    #pragma unroll
    for(int d=1;d<64;d<<=1){ int v=__shfl_up(incl,d); if(lane>=d) incl+=v; }
    if(lane==63) wsum[wid]=incl;
    __syncthreads();
    int woff=0;
    for(int w=0;w<wid;w++) woff+=wsum[w];
    int excl=runs+woff+incl-x;
    if(i<n){ off[i]=excl; cur[i]=excl; }
    __syncthreads();
    if(tid==0){ int t=0; for(int w=0;w<16;w++) t+=wsum[w]; runs+=t; }
    __syncthreads();
  }
  if(tid==0) off[n]=runs;
}

__global__ __launch_bounds__(256) void k_scatter(const int* __restrict__ v_ids, const int* __restrict__ e_ids,
                                                 int* __restrict__ cur_e, int* __restrict__ cur_v,
                                                 int* __restrict__ perm_e, int* __restrict__ perm_v)
{
  int i = blockIdx.x*256+threadIdx.x;
  if(i<NP){
    int pe = atomicAdd(&cur_e[e_ids[i]],1); perm_e[pe]=i;
    int pv = atomicAdd(&cur_v[v_ids[i]],1); perm_v[pv]=i;
  }
}

// ---------- GEMM1: Xp[NV,512] = X[NV,128] @ Wcat[128,512] + bcat ----------
// Wcat col j lives in Wh[j/64][k][j%64]; blockIdx.y = head (BN=64 aligned to head)
__global__ __launch_bounds__(256) void k_gemm1(const float* __restrict__ X, const float* __restrict__ Wh,
                                               const float* __restrict__ bh, float* __restrict__ Xp)
{
  __shared__ float As[32][64];
  __shared__ float Bs[32][64];
  int tid = threadIdx.x;
  int tx = tid & 15, ty = tid >> 4;
  int r0 = blockIdx.x * 64;
  int head = blockIdx.y;
  const float* Wb = Wh + (size_t)head*8192;   // [128,64]
  float acc[4][4] = {};
  for(int k0=0;k0<128;k0+=32){
    #pragma unroll
    for(int rep=0;rep<2;rep++){
      int lin = rep*256 + tid;          // 0..511  (64 rows x 8 float4)
      int row = lin >> 3;
      int q   = lin & 7;
      float4 v = make_float4(0.f,0.f,0.f,0.f);
      int gr = r0+row;
      if(gr < NV) v = *(const float4*)(X + (size_t)gr*128 + k0 + q*4);
      As[q*4+0][row]=v.x; As[q*4+1][row]=v.y; As[q*4+2][row]=v.z; As[q*4+3][row]=v.w;
    }
    #pragma unroll
    for(int rep=0;rep<2;rep++){
      int lin = rep*256 + tid;          // 0..511  (32 k x 16 float4)
      int kk = lin >> 4;
      int q  = lin & 15;
      *(float4*)&Bs[kk][q*4] = *(const float4*)(Wb + (size_t)(k0+kk)*64 + q*4);
    }
    __syncthreads();
    #pragma unroll
    for(int k=0;k<32;k++){
      float4 a = *(const float4*)&As[k][ty*4];
      float4 b = *(const float4*)&Bs[k][tx*4];
      acc[0][0]+=a.x*b.x; acc[0][1]+=a.x*b.y; acc[0][2]+=a.x*b.z; acc[0][3]+=a.x*b.w;
      acc[1][0]+=a.y*b.x; acc[1][1]+=a.y*b.y; acc[1][2]+=a.y*b.z; acc[1][3]+=a.y*b.w;
      acc[2][0]+=a.z*b.x; acc[2][1]+=a.z*b.y; acc[2][2]+=a.z*b.z; acc[2][3]+=a.z*b.w;
      acc[3][0]+=a.w*b.x; acc[3][1]+=a.w*b.y; acc[3][2]+=a.w*b.z; acc[3][3]+=a.w*b.w;
    }
    __syncthreads();
  }
  int n0 = head*64 + tx*4;
  float4 bias = *(const float4*)(bh + n0);
  #pragma unroll
  for(int i=0;i<4;i++){
    int gr = r0 + ty*4 + i;
    if(gr<NV){
      float4 o = make_float4(acc[i][0]+bias.x, acc[i][1]+bias.y, acc[i][2]+bias.z, acc[i][3]+bias.w);
      *(float4*)(Xp + (size_t)gr*CH + n0) = o;
    }
  }
}

// ---------- per-pair scores, 8 heads (C=512) ----------
// s[p][h] = leaky(dot(rows[gid[p]][64h:64h+64], avec[64h:64h+64])) ; atomicMax into mseg[sid[p]][h]
__global__ __launch_bounds__(256) void k_scores8(const float* __restrict__ rows,
                                                 const int* __restrict__ gid,
                                                 const int* __restrict__ sid,
                                                 const float* __restrict__ avec,
                                                 float* __restrict__ sout,
                                                 unsigned* __restrict__ mseg)
{
  int lane = threadIdx.x & 63, wid = threadIdx.x >> 6;
  int p = blockIdx.x*4 + wid;
  if(p>=NP) return;
  int g = gid[p];
  const float* r = rows + (size_t)g*CH + lane*8;
  float4 x0 = *(const float4*)r;
  float4 x1 = *(const float4*)(r+4);
  float4 a0 = *(const float4*)(avec + lane*8);
  float4 a1 = *(const float4*)(avec + lane*8 + 4);
  float s = x0.x*a0.x + x0.y*a0.y + x0.z*a0.z + x0.w*a0.w
          + x1.x*a1.x + x1.y*a1.y + x1.z*a1.z + x1.w*a1.w;
  s += __shfl_xor(s,1); s += __shfl_xor(s,2); s += __shfl_xor(s,4);
  s = (s>0.f) ? s : SLOPE*s;
  if((lane&7)==0){
    int h = lane>>3;
    sout[(size_t)p*8+h] = s;
    atomicMax(&mseg[(size_t)sid[p]*8+h], encf(s));
  }
}

// ---------- per-segment softmax-weighted aggregation (C=512, 8 heads) ----------
template<bool RELU>
__global__ __launch_bounds__(256) void k_agg8(const float* __restrict__ rows,
                                              const int* __restrict__ gid,
                                              const int* __restrict__ off,
                                              const int* __restrict__ perm,
                                              const float* __restrict__ sbuf,
                                              const unsigned* __restrict__ mseg,
                                              float* __restrict__ outm)
{
  __shared__ float red[4][CH];
  __shared__ float den_s[8];
  int e = blockIdx.x;
  int s0 = off[e], n = off[e+1]-s0;
  int lane=threadIdx.x&63, wid=threadIdx.x>>6, tid=threadIdx.x;
  if(tid<8) den_s[tid]=0.f;
  __syncthreads();
  // denominator per head
  {
    int hh = tid&7;
    float mloc = decf(mseg[(size_t)e*8+hh]);  // NaN only when n==0 (unused)
    float dp=0.f;
    for(int base=tid; base<n*8; base+=256){
      int i = base>>3;
      int p = perm[s0+i];
      dp += __expf(sbuf[(size_t)p*8+hh] - mloc);
    }
    atomicAdd(&den_s[hh], dp);
  }
  __syncthreads();
  int h = lane>>3;
  float mh = decf(mseg[(size_t)e*8+h]);
  float invd = 1.f/(den_s[h]+1e-9f);
  float acc[8]={0,0,0,0,0,0,0,0};
  for(int i=wid;i<n;i+=4){
    int p = perm[s0+i];
    float al = __expf(sbuf[(size_t)p*8+h] - mh) * invd;
    const float* r = rows + (size_t)gid[p]*CH + lane*8;
    float4 x0 = *(const float4*)r;
    float4 x1 = *(const float4*)(r+4);
    acc[0]+=al*x0.x; acc[1]+=al*x0.y; acc[2]+=al*x0.z; acc[3]+=al*x0.w;
    acc[4]+=al*x1.x; acc[5]+=al*x1.y; acc[6]+=al*x1.z; acc[7]+=al*x1.w;
  }
  #pragma unroll
  for(int j=0;j<8;j++) red[wid][lane*8+j]=acc[j];
  __syncthreads();
  for(int c=tid;c<CH;c+=256){
    float v = red[0][c]+red[1][c]+red[2][c]+red[3][c];
    if(RELU) v = v>0.f ? v : 0.f;
    outm[(size_t)e*CH+c] = v;
  }
}

// ---------- frequency table for pos encoding (double-precision exp once) ----------
__global__ void k_freq(float* __restrict__ freq){
  int c = blockIdx.x*256 + threadIdx.x;
  if(c<CH) freq[c] = (float)exp(-(double)c * 9.210340371976184 / 512.0);
}

// ---------- pos encoding: X += L1(X) * pe  (in place) ----------
__global__ __launch_bounds__(256) void k_pos(float* __restrict__ X, const float* __restrict__ freq)
{
  int lane=threadIdx.x&63, wid=threadIdx.x>>6;
  int v = blockIdx.x*4+wid;
  if(v>=NV) return;
  float* r = X + (size_t)v*CH + lane*8;
  float4 x0=*(float4*)r, x1=*(float4*)(r+4);
  float s = fabsf(x0.x)+fabsf(x0.y)+fabsf(x0.z)+fabsf(x0.w)
          + fabsf(x1.x)+fabsf(x1.y)+fabsf(x1.z)+fabsf(x1.w);
  #pragma unroll
  for(int d=1;d<64;d<<=1) s += __shfl_xor(s,d);
  const float inv = 0.04419417382415922f; // 1/sqrt(512)
  float pos = (float)v;
  float xv[8] = {x0.x,x0.y,x0.z,x0.w,x1.x,x1.y,x1.z,x1.w};
  float o[8];
  #pragma unroll
  for(int j=0;j<8;j++){
    int c = lane*8+j;
    float ang = pos*freq[c];
    float pe = ((c&1)? cosf(ang) : sinf(ang))*inv;
    o[j] = xv[j] + s*pe;
  }
  float4 y0=make_float4(o[0],o[1],o[2],o[3]), y1=make_float4(o[4],o[5],o[6],o[7]);
  *(float4*)r = y0; *(float4*)(r+4)=y1;
}

// ---------- degree-normalized segment average (C=512); optional residual add ----------
__global__ __launch_bounds__(256) void k_avg8(const float* __restrict__ rows,
                                              const int* __restrict__ gid,
                                              const int* __restrict__ off,
                                              const int* __restrict__ perm,
                                              const int* __restrict__ cnt,
                                              const float* __restrict__ addbase,
                                              float* __restrict__ outm)
{
  __shared__ float red[4][CH];
  int e = blockIdx.x;
  int s0=off[e], n=off[e+1]-s0;
  int lane=threadIdx.x&63, wid=threadIdx.x>>6, tid=threadIdx.x;
  float acc[8]={0,0,0,0,0,0,0,0};
  for(int i=wid;i<n;i+=4){
    int p = perm[s0+i];
    const float* r = rows + (size_t)gid[p]*CH + lane*8;
    float4 x0=*(const float4*)r, x1=*(const float4*)(r+4);
    acc[0]+=x0.x; acc[1]+=x0.y; acc[2]+=x0.z; acc[3]+=x0.w;
    acc[4]+=x1.x; acc[5]+=x1.y; acc[6]+=x1.z; acc[7]+=x1.w;
  }
  #pragma unroll
  for(int j=0;j<8;j++) red[wid][lane*8+j]=acc[j];
  __syncthreads();
  int c0 = cnt[e];
  float scale = 1.f/(float)(c0>1?c0:1);
  for(int c=tid;c<CH;c+=256){
    float v=(red[0][c]+red[1][c]+red[2][c]+red[3][c])*scale;
    if(addbase) v += addbase[(size_t)e*CH+c];
    outm[(size_t)e*CH+c]=v;
  }
}

// ---------- GEMM2: Xp2[NV,40] = Xt[NV,512] @ Wo[512,40] + bo ----------
__global__ __launch_bounds__(256) void k_gemm2(const float* __restrict__ Xt, const float* __restrict__ Wo,
                                               const float* __restrict__ bo, float* __restrict__ Xp2)
{
  __shared__ float rs[16*516];   // 16 rows, padded stride 516 (bank-spread, keeps 16B align)
  int tid=threadIdx.x;
  int r0 = blockIdx.x*16;
  for(int lin=tid; lin<2048; lin+=256){     // 16 rows x 128 float4
    int row = lin>>7; int q = lin&127;
    int gr = r0+row;
    float4 v=make_float4(0.f,0.f,0.f,0.f);
    if(gr<NV) v = *(const float4*)(Xt + (size_t)gr*CH + q*4);
    *(float4*)&rs[row*516+q*4] = v;
  }
  __syncthreads();
  for(int idx=tid; idx<16*NC; idx+=256){
    int r = idx/NC, n = idx%NC;
    int gr = r0+r;
    if(gr>=NV) continue;
    const float* rr = &rs[r*516];
    float acc=0.f;
    #pragma unroll 8
    for(int k=0;k<CH;k++) acc += rr[k]*Wo[(size_t)k*NC+n];
    Xp2[(size_t)gr*NC+n] = acc + bo[n];
  }
}

// ---------- per-pair scores (C=40) ----------
__global__ __launch_bounds__(256) void k_scores1(const float* __restrict__ rows,
                                                 const int* __restrict__ gid,
                                                 const int* __restrict__ sid,
                                                 const float* __restrict__ avec,
                                                 float* __restrict__ sout,
                                                 unsigned* __restrict__ mseg)
{
  int lane=threadIdx.x&63, wid=threadIdx.x>>6;
  int p = blockIdx.x*4+wid;
  if(p>=NP) return;
  float x = 0.f;
  if(lane<NC) x = rows[(size_t)gid[p]*NC+lane]*avec[lane];
  #pragma unroll
  for(int d=1;d<64;d<<=1) x += __shfl_xor(x,d);
  if(lane==0){
    float s = (x>0.f)? x : SLOPE*x;
    sout[p]=s;
    atomicMax(&mseg[sid[p]], encf(s));
  }
}

// ---------- per-segment softmax aggregation (C=40) ----------
__global__ __launch_bounds__(256) void k_agg1(const float* __restrict__ rows,
                                              const int* __restrict__ gid,
                                              const int* __restrict__ off,
                                              const int* __restrict__ perm,
                                              const float* __restrict__ sbuf,
                                              const unsigned* __restrict__ mseg,
                                              float* __restrict__ outm)
{
  __shared__ float red[4][NC];
  __shared__ float den_s;
  int e = blockIdx.x;
  int s0=off[e], n=off[e+1]-s0;
  int lane=threadIdx.x&63, wid=threadIdx.x>>6, tid=threadIdx.x;
  float mh = decf(mseg[e]);
  if(tid==0) den_s=0.f;
  __syncthreads();
  float dp=0.f;
  for(int i=tid;i<n;i+=256) dp += __expf(sbuf[perm[s0+i]] - mh);
  #pragma unroll
  for(int d=1;d<64;d<<=1) dp += __shfl_xor(dp,d);
  if(lane==0) atomicAdd(&den_s,dp);
  __syncthreads();
  float invd = 1.f/(den_s+1e-9f);
  float acc=0.f;
  for(int i=wid;i<n;i+=4){
    int p=perm[s0+i];
    float al = __expf(sbuf[p]-mh)*invd;
    float x = (lane<NC)? rows[(size_t)gid[p]*NC+lane] : 0.f;
    acc += al*x;
  }
  if(lane<NC) red[wid][lane]=acc;
  __syncthreads();
  if(tid<NC) outm[(size_t)e*NC+tid] = red[0][tid]+red[1][tid]+red[2][tid]+red[3][tid];
}

// ======================================================================
extern "C" void kernel_launch(void* const* d_in, const int* in_sizes, int n_in,
                              void* d_out, int out_size, void* d_ws, size_t ws_size,
                              hipStream_t stream)
{
  (void)in_sizes; (void)n_in; (void)out_size; (void)ws_size;
  const float* X   = (const float*)d_in[0];
  const float* Wh  = (const float*)d_in[1];
  const float* bh  = (const float*)d_in[2];
  const float* avh = (const float*)d_in[3];
  const float* aeh = (const float*)d_in[4];
  const float* Wo  = (const float*)d_in[5];
  const float* bo  = (const float*)d_in[6];
  const float* avo = (const float*)d_in[7];
  const float* aeo = (const float*)d_in[8];
  const int* v_ids = (const int*)d_in[9];
  const int* e_ids = (const int*)d_in[10];
  float* out = (float*)d_out;

  // ---- workspace carve-up (~167 MB total) ----
  char* w = (char*)d_ws;
  auto alloc = [&](size_t bytes)->char*{ char* p=w; w += (bytes+255)&~(size_t)255; return p; };
  int* cnt_e  = (int*)alloc((size_t)NE*4);
  int* cnt_v  = (int*)alloc((size_t)NV*4);
  int* off_e  = (int*)alloc((size_t)(NE+1)*4);
  int* off_v  = (int*)alloc((size_t)(NV+1)*4);
  int* cur_e  = (int*)alloc((size_t)NE*4);
  int* cur_v  = (int*)alloc((size_t)NV*4);
  int* perm_e = (int*)alloc((size_t)NP*4);
  int* perm_v = (int*)alloc((size_t)NP*4);
  unsigned* m_e8 = (unsigned*)alloc((size_t)NE*8*4);
  unsigned* m_v8 = (unsigned*)alloc((size_t)NV*8*4);
  unsigned* m_e1 = (unsigned*)alloc((size_t)NE*4);
  unsigned* m_v1 = (unsigned*)alloc((size_t)NV*4);
  float* sbuf = (float*)alloc((size_t)NP*8*4);      // reused by every softmax stage
  float* Xp   = (float*)alloc((size_t)NV*CH*4);     // Xp, later Xt (aliased)
  float* Ye   = (float*)alloc((size_t)NE*CH*4);     // Ye, later Xe (aliased)
  float* Xp2  = (float*)alloc((size_t)NV*NC*4);
  float* Ye2  = (float*)alloc((size_t)NE*NC*4);
  float* freq = (float*)alloc((size_t)CH*4);

  // ---- init ----
  hipMemsetAsync(cnt_e, 0, (size_t)NE*4, stream);
  hipMemsetAsync(cnt_v, 0, (size_t)NV*4, stream);
  hipMemsetAsync(m_e8, 0, (size_t)NE*8*4, stream);
  hipMemsetAsync(m_v8, 0, (size_t)NV*8*4, stream);
  hipMemsetAsync(m_e1, 0, (size_t)NE*4, stream);
  hipMemsetAsync(m_v1, 0, (size_t)NV*4, stream);

  const int PB = (NP+255)/256;

  // ---- CSR ----
  k_hist<<<PB,256,0,stream>>>(v_ids,e_ids,cnt_e,cnt_v);
  k_scan<<<1,1024,0,stream>>>(cnt_e,NE,off_e,cur_e);
  k_scan<<<1,1024,0,stream>>>(cnt_v,NV,off_v,cur_v);
  k_scatter<<<PB,256,0,stream>>>(v_ids,e_ids,cur_e,cur_v,perm_e,perm_v);

  // ---- layer 1: multi-head conv ----
  k_gemm1<<<dim3((NV+63)/64, 8),256,0,stream>>>(X,Wh,bh,Xp);
  k_scores8<<<(NP+3)/4,256,0,stream>>>(Xp, v_ids, e_ids, avh, sbuf, m_e8);
  k_agg8<false><<<NE,256,0,stream>>>(Xp, v_ids, off_e, perm_e, sbuf, m_e8, Ye);
  k_scores8<<<(NP+3)/4,256,0,stream>>>(Ye, e_ids, v_ids, aeh, sbuf, m_v8);
  k_agg8<true><<<NV,256,0,stream>>>(Ye, e_ids, off_v, perm_v, sbuf, m_v8, Xp); // Xp now holds Xt

  // ---- pos encoding (in place on Xt) ----
  k_freq<<<2,256,0,stream>>>(freq);
  k_pos<<<(NV+3)/4,256,0,stream>>>(Xp, freq);

  // ---- hspd encoding ----
  k_avg8<<<NE,256,0,stream>>>(Xp, v_ids, off_e, perm_e, cnt_e, nullptr, Ye);   // Ye now holds Xe
  k_avg8<<<NV,256,0,stream>>>(Ye, e_ids, off_v, perm_v, cnt_v, Xp, Xp);        // Xt += hspd (in place)

  // ---- layer 2: output conv (C=40) ----
  k_gemm2<<<(NV+15)/16,256,0,stream>>>(Xp, Wo, bo, Xp2);
  k_scores1<<<(NP+3)/4,256,0,stream>>>(Xp2, v_ids, e_ids, avo, sbuf, m_e1);
  k_agg1<<<NE,256,0,stream>>>(Xp2, v_ids, off_e, perm_e, sbuf, m_e1, Ye2);
  k_scores1<<<(NP+3)/4,256,0,stream>>>(Ye2, e_ids, v_ids, aeo, sbuf, m_v1);
  k_agg1<<<NV,256,0,stream>>>(Ye2, e_ids, off_v, perm_v, sbuf, m_v1, out);
}

// Round 12
// 1758.273 us; speedup vs baseline: 1.4888x; 1.4888x over previous
//
#include <hip/hip_runtime.h>
#include <math.h>

#define NV 50000
#define NE 10000
#define NP 800000
#define CH 512      // HEADS * C_HID
#define NC 40
#define SLOPE 0.2f

// ---------- CSR build ----------
__global__ __launch_bounds__(256) void k_hist(const int* __restrict__ v_ids, const int* __restrict__ e_ids,
                                              int* __restrict__ cnt_e, int* __restrict__ cnt_v)
{
  int i = blockIdx.x*256 + threadIdx.x;
  if(i<NP){ atomicAdd(&cnt_e[e_ids[i]],1); atomicAdd(&cnt_v[v_ids[i]],1); }
}

__global__ __launch_bounds__(1024) void k_scan(const int* __restrict__ cnt, int n,
                                               int* __restrict__ off, int* __restrict__ cur)
{
  __shared__ int wsum[16];
  __shared__ int runs;
  int tid=threadIdx.x, lane=tid&63, wid=tid>>6;
  if(tid==0) runs=0;
  __syncthreads();
  for(int base=0;base<n;base+=1024){
    int i=base+tid;
    int x=(i<n)?cnt[i]:0;
    int incl=x;
    #pragma unroll
    for(int d=1;d<64;d<<=1){ int v=__shfl_up(incl,d); if(lane>=d) incl+=v; }
    if(lane==63) wsum[wid]=incl;
    __syncthreads();
    int woff=0;
    for(int w=0;w<wid;w++) woff+=wsum[w];
    int excl=runs+woff+incl-x;
    if(i<n){ off[i]=excl; cur[i]=excl; }
    __syncthreads();
    if(tid==0){ int t=0; for(int w=0;w<16;w++) t+=wsum[w]; runs+=t; }
    __syncthreads();
  }
  if(tid==0) off[n]=runs;
}

// scatter stores the SOURCE id directly (gsrc_e[k] = v_ids of k-th pair of edge-CSR)
__global__ __launch_bounds__(256) void k_scatter(const int* __restrict__ v_ids, const int* __restrict__ e_ids,
                                                 int* __restrict__ cur_e, int* __restrict__ cur_v,
                                                 int* __restrict__ gsrc_e, int* __restrict__ gsrc_v)
{
  int i = blockIdx.x*256+threadIdx.x;
  if(i<NP){
    int v = v_ids[i], e = e_ids[i];
    int pe = atomicAdd(&cur_e[e],1); gsrc_e[pe]=v;
    int pv = atomicAdd(&cur_v[v],1); gsrc_v[pv]=e;
  }
}

// ---------- GEMM1: Xp[NV,512] = X[NV,128] @ Wcat[128,512] + bcat ----------
__global__ __launch_bounds__(256) void k_gemm1(const float* __restrict__ X, const float* __restrict__ Wh,
                                               const float* __restrict__ bh, float* __restrict__ Xp)
{
  __shared__ float As[32][64];
  __shared__ float Bs[32][64];
  int tid = threadIdx.x;
  int tx = tid & 15, ty = tid >> 4;
  int r0 = blockIdx.x * 64;
  int head = blockIdx.y;
  const float* Wb = Wh + (size_t)head*8192;   // [128,64]
  float acc[4][4] = {};
  for(int k0=0;k0<128;k0+=32){
    #pragma unroll
    for(int rep=0;rep<2;rep++){
      int lin = rep*256 + tid;          // 64 rows x 8 float4
      int row = lin >> 3;
      int q   = lin & 7;
      float4 v = make_float4(0.f,0.f,0.f,0.f);
      int gr = r0+row;
      if(gr < NV) v = *(const float4*)(X + (size_t)gr*128 + k0 + q*4);
      As[q*4+0][row]=v.x; As[q*4+1][row]=v.y; As[q*4+2][row]=v.z; As[q*4+3][row]=v.w;
    }
    #pragma unroll
    for(int rep=0;rep<2;rep++){
      int lin = rep*256 + tid;          // 32 k x 16 float4
      int kk = lin >> 4;
      int q  = lin & 15;
      *(float4*)&Bs[kk][q*4] = *(const float4*)(Wb + (size_t)(k0+kk)*64 + q*4);
    }
    __syncthreads();
    #pragma unroll
    for(int k=0;k<32;k++){
      float4 a = *(const float4*)&As[k][ty*4];
      float4 b = *(const float4*)&Bs[k][tx*4];
      acc[0][0]+=a.x*b.x; acc[0][1]+=a.x*b.y; acc[0][2]+=a.x*b.z; acc[0][3]+=a.x*b.w;
      acc[1][0]+=a.y*b.x; acc[1][1]+=a.y*b.y; acc[1][2]+=a.y*b.z; acc[1][3]+=a.y*b.w;
      acc[2][0]+=a.z*b.x; acc[2][1]+=a.z*b.y; acc[2][2]+=a.z*b.z; acc[2][3]+=a.z*b.w;
      acc[3][0]+=a.w*b.x; acc[3][1]+=a.w*b.y; acc[3][2]+=a.w*b.z; acc[3][3]+=a.w*b.w;
    }
    __syncthreads();
  }
  int n0 = head*64 + tx*4;
  float4 bias = *(const float4*)(bh + n0);
  #pragma unroll
  for(int i=0;i<4;i++){
    int gr = r0 + ty*4 + i;
    if(gr<NV){
      float4 o = make_float4(acc[i][0]+bias.x, acc[i][1]+bias.y, acc[i][2]+bias.z, acc[i][3]+bias.w);
      *(float4*)(Xp + (size_t)gr*CH + n0) = o;
    }
  }
}

// ---------- per-ROW scores, 8 heads (C=512): rsc[r][h] = leaky(dot(row, avec_head)) ----------
__global__ __launch_bounds__(256) void k_rowscore8(const float* __restrict__ rows, int nr,
                                                   const float* __restrict__ avec,
                                                   float* __restrict__ rsc)
{
  int lane=threadIdx.x&63, wid=threadIdx.x>>6;
  int r = blockIdx.x*4+wid;
  if(r>=nr) return;
  const float* rr = rows + (size_t)r*CH + lane*8;
  float4 a0 = *(const float4*)(avec + lane*8);
  float4 a1 = *(const float4*)(avec + lane*8 + 4);
  float4 x0 = *(const float4*)rr;
  float4 x1 = *(const float4*)(rr+4);
  float s = x0.x*a0.x + x0.y*a0.y + x0.z*a0.z + x0.w*a0.w
          + x1.x*a1.x + x1.y*a1.y + x1.z*a1.z + x1.w*a1.w;
  s += __shfl_xor(s,1); s += __shfl_xor(s,2); s += __shfl_xor(s,4);
  s = (s>0.f) ? s : SLOPE*s;
  if((lane&7)==0) rsc[(size_t)r*8 + (lane>>3)] = s;
}

// ---------- per-ROW score (C=40) ----------
__global__ __launch_bounds__(256) void k_rowscore1(const float* __restrict__ rows, int nr,
                                                   const float* __restrict__ avec,
                                                   float* __restrict__ rsc)
{
  int lane=threadIdx.x&63, wid=threadIdx.x>>6;
  int r = blockIdx.x*4+wid;
  if(r>=nr) return;
  float x = (lane<NC)? rows[(size_t)r*NC+lane]*avec[lane] : 0.f;
  #pragma unroll
  for(int d=1;d<64;d<<=1) x += __shfl_xor(x,d);
  if(lane==0) rsc[r] = (x>0.f)? x : SLOPE*x;
}

// ---------- segment softmax aggregation, self-contained (C=512, 8 heads) ----------
// 3 sweeps: max (L2 tables), denom (L2 tables), weighted row gather (the big one)
template<bool RELU>
__global__ __launch_bounds__(256) void k_agg8(const float* __restrict__ rows,
                                              const int* __restrict__ gsrc,
                                              const int* __restrict__ off,
                                              const float* __restrict__ rsc,
                                              float* __restrict__ outm)
{
  __shared__ float red[4][CH];
  __shared__ float part[4][8];
  __shared__ float mh_s[8], dn_s[8];
  int e = blockIdx.x;
  int s0 = off[e], n = off[e+1]-s0;
  int tid=threadIdx.x, lane=tid&63, wid=tid>>6;
  int h8 = tid&7;
  // ---- sweep 1: segment max per head ----
  float mloc = -INFINITY;
  for(int i=tid>>3; i<n; i+=32)
    mloc = fmaxf(mloc, rsc[(size_t)gsrc[s0+i]*8 + h8]);
  mloc = fmaxf(mloc, __shfl_xor(mloc,8));
  mloc = fmaxf(mloc, __shfl_xor(mloc,16));
  mloc = fmaxf(mloc, __shfl_xor(mloc,32));
  if(lane<8) part[wid][lane]=mloc;
  __syncthreads();
  if(tid<8) mh_s[tid] = fmaxf(fmaxf(part[0][tid],part[1][tid]), fmaxf(part[2][tid],part[3][tid]));
  __syncthreads();
  // ---- sweep 2: denominator per head ----
  float mh8 = mh_s[h8];
  float dp = 0.f;
  for(int i=tid>>3; i<n; i+=32)
    dp += __expf(rsc[(size_t)gsrc[s0+i]*8 + h8] - mh8);
  dp += __shfl_xor(dp,8); dp += __shfl_xor(dp,16); dp += __shfl_xor(dp,32);
  if(lane<8) part[wid][lane]=dp;
  __syncthreads();
  if(tid<8) dn_s[tid] = part[0][tid]+part[1][tid]+part[2][tid]+part[3][tid];
  __syncthreads();
  // ---- sweep 3: weighted row gather ----
  int h = lane>>3;
  float mh = mh_s[h];
  float invd = 1.f/(dn_s[h]+1e-9f);
  float acc[8]={0,0,0,0,0,0,0,0};
  for(int i=wid;i<n;i+=4){
    int g = gsrc[s0+i];
    float al = __expf(rsc[(size_t)g*8+h] - mh) * invd;
    const float* r = rows + (size_t)g*CH + lane*8;
    float4 x0 = *(const float4*)r;
    float4 x1 = *(const float4*)(r+4);
    acc[0]+=al*x0.x; acc[1]+=al*x0.y; acc[2]+=al*x0.z; acc[3]+=al*x0.w;
    acc[4]+=al*x1.x; acc[5]+=al*x1.y; acc[6]+=al*x1.z; acc[7]+=al*x1.w;
  }
  #pragma unroll
  for(int j=0;j<8;j++) red[wid][lane*8+j]=acc[j];
  __syncthreads();
  for(int c=tid;c<CH;c+=256){
    float v = red[0][c]+red[1][c]+red[2][c]+red[3][c];
    if(RELU) v = v>0.f ? v : 0.f;
    outm[(size_t)e*CH+c] = v;
  }
}

// ---------- frequency table for pos encoding ----------
__global__ void k_freq(float* __restrict__ freq){
  int c = blockIdx.x*256 + threadIdx.x;
  if(c<CH) freq[c] = (float)exp(-(double)c * 9.210340371976184 / 512.0);
}

// ---------- pos encoding: X += L1(X) * pe  (in place) ----------
__global__ __launch_bounds__(256) void k_pos(float* __restrict__ X, const float* __restrict__ freq)
{
  int lane=threadIdx.x&63, wid=threadIdx.x>>6;
  int v = blockIdx.x*4+wid;
  if(v>=NV) return;
  float* r = X + (size_t)v*CH + lane*8;
  float4 x0=*(float4*)r, x1=*(float4*)(r+4);
  float s = fabsf(x0.x)+fabsf(x0.y)+fabsf(x0.z)+fabsf(x0.w)
          + fabsf(x1.x)+fabsf(x1.y)+fabsf(x1.z)+fabsf(x1.w);
  #pragma unroll
  for(int d=1;d<64;d<<=1) s += __shfl_xor(s,d);
  const float inv = 0.04419417382415922f; // 1/sqrt(512)
  float pos = (float)v;
  float xv[8] = {x0.x,x0.y,x0.z,x0.w,x1.x,x1.y,x1.z,x1.w};
  float o[8];
  #pragma unroll
  for(int j=0;j<8;j++){
    int c = lane*8+j;
    float ang = pos*freq[c];
    float pe = ((c&1)? cosf(ang) : sinf(ang))*inv;
    o[j] = xv[j] + s*pe;
  }
  float4 y0=make_float4(o[0],o[1],o[2],o[3]), y1=make_float4(o[4],o[5],o[6],o[7]);
  *(float4*)r = y0; *(float4*)(r+4)=y1;
}

// ---------- degree-normalized segment average (C=512); optional residual add ----------
__global__ __launch_bounds__(256) void k_avg8(const float* __restrict__ rows,
                                              const int* __restrict__ gsrc,
                                              const int* __restrict__ off,
                                              const int* __restrict__ cnt,
                                              const float* __restrict__ addbase,
                                              float* __restrict__ outm)
{
  __shared__ float red[4][CH];
  int e = blockIdx.x;
  int s0=off[e], n=off[e+1]-s0;
  int lane=threadIdx.x&63, wid=threadIdx.x>>6, tid=threadIdx.x;
  float acc[8]={0,0,0,0,0,0,0,0};
  for(int i=wid;i<n;i+=4){
    int g = gsrc[s0+i];
    const float* r = rows + (size_t)g*CH + lane*8;
    float4 x0=*(const float4*)r, x1=*(const float4*)(r+4);
    acc[0]+=x0.x; acc[1]+=x0.y; acc[2]+=x0.z; acc[3]+=x0.w;
    acc[4]+=x1.x; acc[5]+=x1.y; acc[6]+=x1.z; acc[7]+=x1.w;
  }
  #pragma unroll
  for(int j=0;j<8;j++) red[wid][lane*8+j]=acc[j];
  __syncthreads();
  int c0 = cnt[e];
  float scale = 1.f/(float)(c0>1?c0:1);
  for(int c=tid;c<CH;c+=256){
    float v=(red[0][c]+red[1][c]+red[2][c]+red[3][c])*scale;
    if(addbase) v += addbase[(size_t)e*CH+c];
    outm[(size_t)e*CH+c]=v;
  }
}

// ---------- GEMM2: Xp2[NV,40] = Xt[NV,512] @ Wo[512,40] + bo ----------
__global__ __launch_bounds__(256) void k_gemm2(const float* __restrict__ Xt, const float* __restrict__ Wo,
                                               const float* __restrict__ bo, float* __restrict__ Xp2)
{
  __shared__ float rs[16*516];
  int tid=threadIdx.x;
  int r0 = blockIdx.x*16;
  for(int lin=tid; lin<2048; lin+=256){
    int row = lin>>7; int q = lin&127;
    int gr = r0+row;
    float4 v=make_float4(0.f,0.f,0.f,0.f);
    if(gr<NV) v = *(const float4*)(Xt + (size_t)gr*CH + q*4);
    *(float4*)&rs[row*516+q*4] = v;
  }
  __syncthreads();
  for(int idx=tid; idx<16*NC; idx+=256){
    int r = idx/NC, n = idx%NC;
    int gr = r0+r;
    if(gr>=NV) continue;
    const float* rr = &rs[r*516];
    float acc=0.f;
    #pragma unroll 8
    for(int k=0;k<CH;k++) acc += rr[k]*Wo[(size_t)k*NC+n];
    Xp2[(size_t)gr*NC+n] = acc + bo[n];
  }
}

// ---------- segment softmax aggregation, self-contained (C=40) ----------
__global__ __launch_bounds__(256) void k_agg1(const float* __restrict__ rows,
                                              const int* __restrict__ gsrc,
                                              const int* __restrict__ off,
                                              const float* __restrict__ rsc,
                                              float* __restrict__ outm)
{
  __shared__ float red[4][NC];
  __shared__ float part[4];
  __shared__ float mh_sh, dn_sh;
  int e = blockIdx.x;
  int s0=off[e], n=off[e+1]-s0;
  int tid=threadIdx.x, lane=tid&63, wid=tid>>6;
  // ---- sweep 1: max ----
  float mloc=-INFINITY;
  for(int i=tid;i<n;i+=256) mloc=fmaxf(mloc, rsc[gsrc[s0+i]]);
  #pragma unroll
  for(int d=1;d<64;d<<=1) mloc=fmaxf(mloc,__shfl_xor(mloc,d));
  if(lane==0) part[wid]=mloc;
  __syncthreads();
  if(tid==0) mh_sh = fmaxf(fmaxf(part[0],part[1]),fmaxf(part[2],part[3]));
  __syncthreads();
  float mh = mh_sh;
  // ---- sweep 2: denominator ----
  float dp=0.f;
  for(int i=tid;i<n;i+=256) dp += __expf(rsc[gsrc[s0+i]] - mh);
  #pragma unroll
  for(int d=1;d<64;d<<=1) dp += __shfl_xor(dp,d);
  if(lane==0) part[wid]=dp;
  __syncthreads();
  if(tid==0) dn_sh = part[0]+part[1]+part[2]+part[3];
  __syncthreads();
  float invd = 1.f/(dn_sh+1e-9f);
  // ---- sweep 3: weighted gather ----
  float acc=0.f;
  for(int i=wid;i<n;i+=4){
    int g = gsrc[s0+i];
    float al = __expf(rsc[g]-mh)*invd;
    float x = (lane<NC)? rows[(size_t)g*NC+lane] : 0.f;
    acc += al*x;
  }
  if(lane<NC) red[wid][lane]=acc;
  __syncthreads();
  if(tid<NC) outm[(size_t)e*NC+tid] = red[0][tid]+red[1][tid]+red[2][tid]+red[3][tid];
}

// ======================================================================
extern "C" void kernel_launch(void* const* d_in, const int* in_sizes, int n_in,
                              void* d_out, int out_size, void* d_ws, size_t ws_size,
                              hipStream_t stream)
{
  (void)in_sizes; (void)n_in; (void)out_size; (void)ws_size;
  const float* X   = (const float*)d_in[0];
  const float* Wh  = (const float*)d_in[1];
  const float* bh  = (const float*)d_in[2];
  const float* avh = (const float*)d_in[3];
  const float* aeh = (const float*)d_in[4];
  const float* Wo  = (const float*)d_in[5];
  const float* bo  = (const float*)d_in[6];
  const float* avo = (const float*)d_in[7];
  const float* aeo = (const float*)d_in[8];
  const int* v_ids = (const int*)d_in[9];
  const int* e_ids = (const int*)d_in[10];
  float* out = (float*)d_out;

  // ---- workspace carve-up (~148 MB) ----
  char* w = (char*)d_ws;
  auto alloc = [&](size_t bytes)->char*{ char* p=w; w += (bytes+255)&~(size_t)255; return p; };
  int* cnt_e  = (int*)alloc((size_t)NE*4);
  int* cnt_v  = (int*)alloc((size_t)NV*4);
  int* off_e  = (int*)alloc((size_t)(NE+1)*4);
  int* off_v  = (int*)alloc((size_t)(NV+1)*4);
  int* cur_e  = (int*)alloc((size_t)NE*4);
  int* cur_v  = (int*)alloc((size_t)NV*4);
  int* gsrc_e = (int*)alloc((size_t)NP*4);
  int* gsrc_v = (int*)alloc((size_t)NP*4);
  float* rsc_v = (float*)alloc((size_t)NV*8*4);   // row scores layer1 stage1
  float* rsc_e = (float*)alloc((size_t)NE*8*4);   // row scores layer1 stage2
  float* rs1_v = (float*)alloc((size_t)NV*4);     // row scores layer2 stage1
  float* rs1_e = (float*)alloc((size_t)NE*4);     // row scores layer2 stage2
  float* Xp   = (float*)alloc((size_t)NV*CH*4);   // Xp, later Xt (aliased)
  float* Ye   = (float*)alloc((size_t)NE*CH*4);   // Ye, later Xe (aliased)
  float* Xp2  = (float*)alloc((size_t)NV*NC*4);
  float* Ye2  = (float*)alloc((size_t)NE*NC*4);
  float* freq = (float*)alloc((size_t)CH*4);

  // ---- init ----
  hipMemsetAsync(cnt_e, 0, (size_t)NE*4, stream);
  hipMemsetAsync(cnt_v, 0, (size_t)NV*4, stream);

  const int PB = (NP+255)/256;

  // ---- CSR ----
  k_hist<<<PB,256,0,stream>>>(v_ids,e_ids,cnt_e,cnt_v);
  k_scan<<<1,1024,0,stream>>>(cnt_e,NE,off_e,cur_e);
  k_scan<<<1,1024,0,stream>>>(cnt_v,NV,off_v,cur_v);
  k_scatter<<<PB,256,0,stream>>>(v_ids,e_ids,cur_e,cur_v,gsrc_e,gsrc_v);

  // ---- layer 1: multi-head conv ----
  k_gemm1<<<dim3((NV+63)/64, 8),256,0,stream>>>(X,Wh,bh,Xp);
  k_rowscore8<<<(NV+3)/4,256,0,stream>>>(Xp, NV, avh, rsc_v);
  k_agg8<false><<<NE,256,0,stream>>>(Xp, gsrc_e, off_e, rsc_v, Ye);
  k_rowscore8<<<(NE+3)/4,256,0,stream>>>(Ye, NE, aeh, rsc_e);
  k_agg8<true><<<NV,256,0,stream>>>(Ye, gsrc_v, off_v, rsc_e, Xp); // Xp now holds Xt

  // ---- pos encoding (in place on Xt) ----
  k_freq<<<2,256,0,stream>>>(freq);
  k_pos<<<(NV+3)/4,256,0,stream>>>(Xp, freq);

  // ---- hspd encoding ----
  k_avg8<<<NE,256,0,stream>>>(Xp, gsrc_e, off_e, cnt_e, nullptr, Ye);   // Ye now holds Xe
  k_avg8<<<NV,256,0,stream>>>(Ye, gsrc_v, off_v, cnt_v, Xp, Xp);        // Xt += hspd (in place)

  // ---- layer 2: output conv (C=40) ----
  k_gemm2<<<(NV+15)/16,256,0,stream>>>(Xp, Wo, bo, Xp2);
  k_rowscore1<<<(NV+3)/4,256,0,stream>>>(Xp2, NV, avo, rs1_v);
  k_agg1<<<NE,256,0,stream>>>(Xp2, gsrc_e, off_e, rs1_v, Ye2);
  k_rowscore1<<<(NE+3)/4,256,0,stream>>>(Ye2, NE, aeo, rs1_e);
  k_agg1<<<NV,256,0,stream>>>(Ye2, gsrc_v, off_v, rs1_e, out);
}

// Round 14
// 1693.099 us; speedup vs baseline: 1.5461x; 1.0385x over previous
//
#include <hip/hip_runtime.h>
#include <math.h>

#define NV 50000
#define NE 10000
#define NP 800000
#define CH 512      // HEADS * C_HID
#define NC 40
#define SLOPE 0.2f
#define PINV 0.04419417382415922f   // 1/sqrt(512)

// ---------- CSR build ----------
__global__ __launch_bounds__(256) void k_hist(const int* __restrict__ v_ids, const int* __restrict__ e_ids,
                                              int* __restrict__ cnt_e, int* __restrict__ cnt_v)
{
  int i = blockIdx.x*256 + threadIdx.x;
  if(i<NP){ atomicAdd(&cnt_e[e_ids[i]],1); atomicAdd(&cnt_v[v_ids[i]],1); }
}

// single-block scan, 8 elems/thread (8192/iter)
__global__ __launch_bounds__(1024) void k_scan(const int* __restrict__ cnt, int n,
                                               int* __restrict__ off, int* __restrict__ cur)
{
  __shared__ int wsum[16];
  __shared__ int runs;
  int tid=threadIdx.x, lane=tid&63, wid=tid>>6;
  if(tid==0) runs=0;
  __syncthreads();
  for(int base=0;base<n;base+=8192){
    int i0 = base + tid*8;
    int x[8]; int tsum=0;
    #pragma unroll
    for(int j=0;j<8;j++){ x[j] = (i0+j<n)?cnt[i0+j]:0; tsum+=x[j]; }
    int incl=tsum;
    #pragma unroll
    for(int d=1;d<64;d<<=1){ int v=__shfl_up(incl,d); if(lane>=d) incl+=v; }
    if(lane==63) wsum[wid]=incl;
    __syncthreads();
    int woff=0;
    for(int w=0;w<wid;w++) woff+=wsum[w];
    int run = runs + woff + incl - tsum;
    #pragma unroll
    for(int j=0;j<8;j++){
      if(i0+j<n){ off[i0+j]=run; cur[i0+j]=run; }
      run += x[j];
    }
    __syncthreads();
    if(tid==0){ int t=0; for(int w=0;w<16;w++) t+=wsum[w]; runs+=t; }
    __syncthreads();
  }
  if(tid==0) off[n]=runs;
}

// scatter stores the SOURCE id directly
__global__ __launch_bounds__(256) void k_scatter(const int* __restrict__ v_ids, const int* __restrict__ e_ids,
                                                 int* __restrict__ cur_e, int* __restrict__ cur_v,
                                                 int* __restrict__ gsrc_e, int* __restrict__ gsrc_v)
{
  int i = blockIdx.x*256+threadIdx.x;
  if(i<NP){
    int v = v_ids[i], e = e_ids[i];
    int pe = atomicAdd(&cur_e[e],1); gsrc_e[pe]=v;
    int pv = atomicAdd(&cur_v[v],1); gsrc_v[pv]=e;
  }
}

// ---------- GEMM1 + fused per-row head score ----------
// Xp[NV,512] = X @ Wcat + bcat ; rsc_v[r][head] = leaky(dot(Xp_row_headcols, avh_head))
__global__ __launch_bounds__(256) void k_gemm1(const float* __restrict__ X, const float* __restrict__ Wh,
                                               const float* __restrict__ bh, const float* __restrict__ avh,
                                               float* __restrict__ Xp, float* __restrict__ rsc_v)
{
  __shared__ float As[32][64];
  __shared__ float Bs[32][64];
  __shared__ float scp[64][17];
  int tid = threadIdx.x;
  int tx = tid & 15, ty = tid >> 4;
  int r0 = blockIdx.x * 64;
  int head = blockIdx.y;
  const float* Wb = Wh + (size_t)head*8192;   // [128,64]
  float acc[4][4] = {};
  for(int k0=0;k0<128;k0+=32){
    #pragma unroll
    for(int rep=0;rep<2;rep++){
      int lin = rep*256 + tid;          // 64 rows x 8 float4
      int row = lin >> 3;
      int q   = lin & 7;
      float4 v = make_float4(0.f,0.f,0.f,0.f);
      int gr = r0+row;
      if(gr < NV) v = *(const float4*)(X + (size_t)gr*128 + k0 + q*4);
      As[q*4+0][row]=v.x; As[q*4+1][row]=v.y; As[q*4+2][row]=v.z; As[q*4+3][row]=v.w;
    }
    #pragma unroll
    for(int rep=0;rep<2;rep++){
      int lin = rep*256 + tid;          // 32 k x 16 float4
      int kk = lin >> 4;
      int q  = lin & 15;
      *(float4*)&Bs[kk][q*4] = *(const float4*)(Wb + (size_t)(k0+kk)*64 + q*4);
    }
    __syncthreads();
    #pragma unroll
    for(int k=0;k<32;k++){
      float4 a = *(const float4*)&As[k][ty*4];
      float4 b = *(const float4*)&Bs[k][tx*4];
      acc[0][0]+=a.x*b.x; acc[0][1]+=a.x*b.y; acc[0][2]+=a.x*b.z; acc[0][3]+=a.x*b.w;
      acc[1][0]+=a.y*b.x; acc[1][1]+=a.y*b.y; acc[1][2]+=a.y*b.z; acc[1][3]+=a.y*b.w;
      acc[2][0]+=a.z*b.x; acc[2][1]+=a.z*b.y; acc[2][2]+=a.z*b.z; acc[2][3]+=a.z*b.w;
      acc[3][0]+=a.w*b.x; acc[3][1]+=a.w*b.y; acc[3][2]+=a.w*b.z; acc[3][3]+=a.w*b.w;
    }
    __syncthreads();
  }
  int n0 = head*64 + tx*4;
  float4 bias = *(const float4*)(bh + n0);
  float4 av   = *(const float4*)(avh + n0);
  #pragma unroll
  for(int i=0;i<4;i++){
    int gr = r0 + ty*4 + i;
    float4 o = make_float4(acc[i][0]+bias.x, acc[i][1]+bias.y, acc[i][2]+bias.z, acc[i][3]+bias.w);
    if(gr<NV) *(float4*)(Xp + (size_t)gr*CH + n0) = o;
    scp[ty*4+i][tx] = o.x*av.x + o.y*av.y + o.z*av.z + o.w*av.w;
  }
  __syncthreads();
  if(tid<64){
    int gr = r0 + tid;
    if(gr<NV){
      float s=0.f;
      #pragma unroll
      for(int t=0;t<16;t++) s += scp[tid][t];
      s = (s>0.f)? s : SLOPE*s;
      rsc_v[(size_t)gr*8 + head] = s;
    }
  }
}

// ---------- segment softmax aggregation (C=512, 8 heads), fused epilogues ----------
// MODE 0: pre-relu output + fused row-score (aevec -> rsc_out)
// MODE 1: relu output + fused pos-encoding (freq table, block = vertex id)
template<int MODE>
__global__ __launch_bounds__(256) void k_agg8(const float* __restrict__ rows,
                                              const int* __restrict__ gsrc,
                                              const int* __restrict__ off,
                                              const float* __restrict__ rsc,
                                              float* __restrict__ outm,
                                              const float* __restrict__ aevec,
                                              float* __restrict__ rsc_out,
                                              const float* __restrict__ freq)
{
  __shared__ float red[4][CH];
  __shared__ float part[4][8];
  __shared__ float mh_s[8], dn_s[8];
  __shared__ float sc[CH];      // MODE0 score partials / MODE1: first 256 = L1 partials
  __shared__ float L1s;
  int e = blockIdx.x;
  int s0 = off[e], n = off[e+1]-s0;
  int tid=threadIdx.x, lane=tid&63, wid=tid>>6;
  int h8 = tid&7;
  // ---- sweep 1: segment max per head ----
  float mloc = -INFINITY;
  for(int i=tid>>3; i<n; i+=32)
    mloc = fmaxf(mloc, rsc[(size_t)gsrc[s0+i]*8 + h8]);
  mloc = fmaxf(mloc, __shfl_xor(mloc,8));
  mloc = fmaxf(mloc, __shfl_xor(mloc,16));
  mloc = fmaxf(mloc, __shfl_xor(mloc,32));
  if(lane<8) part[wid][lane]=mloc;
  __syncthreads();
  if(tid<8) mh_s[tid] = fmaxf(fmaxf(part[0][tid],part[1][tid]), fmaxf(part[2][tid],part[3][tid]));
  __syncthreads();
  // ---- sweep 2: denominator per head ----
  float mh8 = mh_s[h8];
  float dp = 0.f;
  for(int i=tid>>3; i<n; i+=32)
    dp += __expf(rsc[(size_t)gsrc[s0+i]*8 + h8] - mh8);
  dp += __shfl_xor(dp,8); dp += __shfl_xor(dp,16); dp += __shfl_xor(dp,32);
  if(lane<8) part[wid][lane]=dp;
  __syncthreads();
  if(tid<8) dn_s[tid] = part[0][tid]+part[1][tid]+part[2][tid]+part[3][tid];
  __syncthreads();
  // ---- sweep 3: weighted row gather ----
  int h = lane>>3;
  float mh = mh_s[h];
  float invd = 1.f/(dn_s[h]+1e-9f);
  float acc[8]={0,0,0,0,0,0,0,0};
  for(int i=wid;i<n;i+=4){
    int g = gsrc[s0+i];
    float al = __expf(rsc[(size_t)g*8+h] - mh) * invd;
    const float* r = rows + (size_t)g*CH + lane*8;
    float4 x0 = *(const float4*)r;
    float4 x1 = *(const float4*)(r+4);
    acc[0]+=al*x0.x; acc[1]+=al*x0.y; acc[2]+=al*x0.z; acc[3]+=al*x0.w;
    acc[4]+=al*x1.x; acc[5]+=al*x1.y; acc[6]+=al*x1.z; acc[7]+=al*x1.w;
  }
  #pragma unroll
  for(int j=0;j<8;j++) red[wid][lane*8+j]=acc[j];
  __syncthreads();
  if(MODE==0){
    for(int c=tid;c<CH;c+=256){
      float v = red[0][c]+red[1][c]+red[2][c]+red[3][c];
      outm[(size_t)e*CH+c] = v;
      sc[c] = v*aevec[c];
    }
    __syncthreads();
    if(tid<8){
      float s=0.f;
      #pragma unroll
      for(int k=0;k<64;k++) s += sc[tid*64+k];
      s = (s>0.f)? s : SLOPE*s;
      rsc_out[(size_t)e*8+tid] = s;
    }
  } else {
    int c0=tid, c1=tid+256;
    float v0 = red[0][c0]+red[1][c0]+red[2][c0]+red[3][c0];
    float v1 = red[0][c1]+red[1][c1]+red[2][c1]+red[3][c1];
    v0 = v0>0.f? v0:0.f;
    v1 = v1>0.f? v1:0.f;
    sc[tid] = v0+v1;                    // relu'd -> |.| = value
    __syncthreads();
    if(tid<64){
      float s = sc[tid]+sc[tid+64]+sc[tid+128]+sc[tid+192];
      #pragma unroll
      for(int d=1;d<64;d<<=1) s += __shfl_xor(s,d);
      if(tid==0) L1s = s;
    }
    __syncthreads();
    float L1 = L1s;
    float pos = (float)e;
    float a0 = pos*freq[c0];
    float p0 = ((c0&1)? cosf(a0) : sinf(a0))*PINV;
    float a1 = pos*freq[c1];
    float p1 = ((c1&1)? cosf(a1) : sinf(a1))*PINV;
    outm[(size_t)e*CH+c0] = v0 + L1*p0;
    outm[(size_t)e*CH+c1] = v1 + L1*p1;
  }
}

// ---------- frequency table for pos encoding ----------
__global__ void k_freq(float* __restrict__ freq){
  int c = blockIdx.x*256 + threadIdx.x;
  if(c<CH) freq[c] = (float)exp(-(double)c * 9.210340371976184 / 512.0);
}

// ---------- degree-normalized segment average (C=512); optional residual add ----------
__global__ __launch_bounds__(256) void k_avg8(const float* __restrict__ rows,
                                              const int* __restrict__ gsrc,
                                              const int* __restrict__ off,
                                              const int* __restrict__ cnt,
                                              const float* __restrict__ addbase,
                                              float* __restrict__ outm)
{
  __shared__ float red[4][CH];
  int e = blockIdx.x;
  int s0=off[e], n=off[e+1]-s0;
  int lane=threadIdx.x&63, wid=threadIdx.x>>6, tid=threadIdx.x;
  float acc[8]={0,0,0,0,0,0,0,0};
  for(int i=wid;i<n;i+=4){
    int g = gsrc[s0+i];
    const float* r = rows + (size_t)g*CH + lane*8;
    float4 x0=*(const float4*)r, x1=*(const float4*)(r+4);
    acc[0]+=x0.x; acc[1]+=x0.y; acc[2]+=x0.z; acc[3]+=x0.w;
    acc[4]+=x1.x; acc[5]+=x1.y; acc[6]+=x1.z; acc[7]+=x1.w;
  }
  #pragma unroll
  for(int j=0;j<8;j++) red[wid][lane*8+j]=acc[j];
  __syncthreads();
  int c0 = cnt[e];
  float scale = 1.f/(float)(c0>1?c0:1);
  for(int c=tid;c<CH;c+=256){
    float v=(red[0][c]+red[1][c]+red[2][c]+red[3][c])*scale;
    if(addbase) v += addbase[(size_t)e*CH+c];
    outm[(size_t)e*CH+c]=v;
  }
}

// ---------- GEMM2 + fused per-row score: Xp2 = Xt @ Wo + bo ; rs1_v = leaky(Xp2 . avo) ----------
__global__ __launch_bounds__(256) void k_gemm2(const float* __restrict__ Xt, const float* __restrict__ Wo,
                                               const float* __restrict__ bo, const float* __restrict__ avo,
                                               float* __restrict__ Xp2, float* __restrict__ rs1_v)
{
  __shared__ float rs[16*516];
  __shared__ float sc2[16][41];
  int tid=threadIdx.x;
  int r0 = blockIdx.x*16;
  for(int lin=tid; lin<2048; lin+=256){
    int row = lin>>7; int q = lin&127;
    int gr = r0+row;
    float4 v=make_float4(0.f,0.f,0.f,0.f);
    if(gr<NV) v = *(const float4*)(Xt + (size_t)gr*CH + q*4);
    *(float4*)&rs[row*516+q*4] = v;
  }
  __syncthreads();
  for(int idx=tid; idx<16*NC; idx+=256){
    int r = idx/NC, n = idx%NC;
    int gr = r0+r;
    if(gr>=NV) continue;
    const float* rr = &rs[r*516];
    float acc=0.f;
    #pragma unroll 8
    for(int k=0;k<CH;k++) acc += rr[k]*Wo[(size_t)k*NC+n];
    float o = acc + bo[n];
    Xp2[(size_t)gr*NC+n] = o;
    sc2[r][n] = o*avo[n];
  }
  __syncthreads();
  if(tid<16){
    int gr = r0+tid;
    if(gr<NV){
      float s=0.f;
      #pragma unroll
      for(int k=0;k<NC;k++) s += sc2[tid][k];
      s = (s>0.f)? s : SLOPE*s;
      rs1_v[gr] = s;
    }
  }
}

// ---------- segment softmax aggregation (C=40), optional fused row-score ----------
template<bool SC>
__global__ __launch_bounds__(256) void k_agg1(const float* __restrict__ rows,
                                              const int* __restrict__ gsrc,
                                              const int* __restrict__ off,
                                              const float* __restrict__ rsc,
                                              float* __restrict__ outm,
                                              const float* __restrict__ aevec,
                                              float* __restrict__ rsout)
{
  __shared__ float red[4][NC];
  __shared__ float part[4];
  __shared__ float mh_sh, dn_sh;
  __shared__ float scb[NC];
  int e = blockIdx.x;
  int s0=off[e], n=off[e+1]-s0;
  int tid=threadIdx.x, lane=tid&63, wid=tid>>6;
  // ---- sweep 1: max ----
  float mloc=-INFINITY;
  for(int i=tid;i<n;i+=256) mloc=fmaxf(mloc, rsc[gsrc[s0+i]]);
  #pragma unroll
  for(int d=1;d<64;d<<=1) mloc=fmaxf(mloc,__shfl_xor(mloc,d));
  if(lane==0) part[wid]=mloc;
  __syncthreads();
  if(tid==0) mh_sh = fmaxf(fmaxf(part[0],part[1]),fmaxf(part[2],part[3]));
  __syncthreads();
  float mh = mh_sh;
  // ---- sweep 2: denominator ----
  float dp=0.f;
  for(int i=tid;i<n;i+=256) dp += __expf(rsc[gsrc[s0+i]] - mh);
  #pragma unroll
  for(int d=1;d<64;d<<=1) dp += __shfl_xor(dp,d);
  if(lane==0) part[wid]=dp;
  __syncthreads();
  if(tid==0) dn_sh = part[0]+part[1]+part[2]+part[3];
  __syncthreads();
  float invd = 1.f/(dn_sh+1e-9f);
  // ---- sweep 3: weighted gather ----
  float acc=0.f;
  for(int i=wid;i<n;i+=4){
    int g = gsrc[s0+i];
    float al = __expf(rsc[g]-mh)*invd;
    float x = (lane<NC)? rows[(size_t)g*NC+lane] : 0.f;
    acc += al*x;
  }
  if(lane<NC) red[wid][lane]=acc;
  __syncthreads();
  if(tid<NC){
    float val = red[0][tid]+red[1][tid]+red[2][tid]+red[3][tid];
    outm[(size_t)e*NC+tid] = val;
    if(SC) scb[tid] = val*aevec[tid];
  }
  if(SC){
    __syncthreads();
    if(tid==0){
      float s=0.f;
      #pragma unroll
      for(int k=0;k<NC;k++) s += scb[k];
      rsout[e] = (s>0.f)? s : SLOPE*s;
    }
  }
}

// ======================================================================
extern "C" void kernel_launch(void* const* d_in, const int* in_sizes, int n_in,
                              void* d_out, int out_size, void* d_ws, size_t ws_size,
                              hipStream_t stream)
{
  (void)in_sizes; (void)n_in; (void)out_size; (void)ws_size;
  const float* X   = (const float*)d_in[0];
  const float* Wh  = (const float*)d_in[1];
  const float* bh  = (const float*)d_in[2];
  const float* avh = (const float*)d_in[3];
  const float* aeh = (const float*)d_in[4];
  const float* Wo  = (const float*)d_in[5];
  const float* bo  = (const float*)d_in[6];
  const float* avo = (const float*)d_in[7];
  const float* aeo = (const float*)d_in[8];
  const int* v_ids = (const int*)d_in[9];
  const int* e_ids = (const int*)d_in[10];
  float* out = (float*)d_out;

  // ---- workspace carve-up (~148 MB) ----
  char* w = (char*)d_ws;
  auto alloc = [&](size_t bytes)->char*{ char* p=w; w += (bytes+255)&~(size_t)255; return p; };
  int* cnt_e  = (int*)alloc((size_t)NE*4);
  int* cnt_v  = (int*)alloc((size_t)NV*4);
  int* off_e  = (int*)alloc((size_t)(NE+1)*4);
  int* off_v  = (int*)alloc((size_t)(NV+1)*4);
  int* cur_e  = (int*)alloc((size_t)NE*4);
  int* cur_v  = (int*)alloc((size_t)NV*4);
  int* gsrc_e = (int*)alloc((size_t)NP*4);
  int* gsrc_v = (int*)alloc((size_t)NP*4);
  float* rsc_v = (float*)alloc((size_t)NV*8*4);
  float* rsc_e = (float*)alloc((size_t)NE*8*4);
  float* rs1_v = (float*)alloc((size_t)NV*4);
  float* rs1_e = (float*)alloc((size_t)NE*4);
  float* Xp   = (float*)alloc((size_t)NV*CH*4);   // Xp, later Xt (aliased)
  float* Ye   = (float*)alloc((size_t)NE*CH*4);   // Ye, later Xe (aliased)
  float* Xp2  = (float*)alloc((size_t)NV*NC*4);
  float* Ye2  = (float*)alloc((size_t)NE*NC*4);
  float* freq = (float*)alloc((size_t)CH*4);

  // ---- init ----
  k_freq<<<2,256,0,stream>>>(freq);
  hipMemsetAsync(cnt_e, 0, (size_t)NE*4, stream);
  hipMemsetAsync(cnt_v, 0, (size_t)NV*4, stream);

  const int PB = (NP+255)/256;

  // ---- CSR ----
  k_hist<<<PB,256,0,stream>>>(v_ids,e_ids,cnt_e,cnt_v);
  k_scan<<<1,1024,0,stream>>>(cnt_e,NE,off_e,cur_e);
  k_scan<<<1,1024,0,stream>>>(cnt_v,NV,off_v,cur_v);
  k_scatter<<<PB,256,0,stream>>>(v_ids,e_ids,cur_e,cur_v,gsrc_e,gsrc_v);

  // ---- layer 1: multi-head conv (scores fused) ----
  k_gemm1<<<dim3((NV+63)/64, 8),256,0,stream>>>(X,Wh,bh,avh,Xp,rsc_v);
  k_agg8<0><<<NE,256,0,stream>>>(Xp, gsrc_e, off_e, rsc_v, Ye, aeh, rsc_e, nullptr);
  k_agg8<1><<<NV,256,0,stream>>>(Ye, gsrc_v, off_v, rsc_e, Xp, nullptr, nullptr, freq); // Xt + posenc

  // ---- hspd encoding ----
  k_avg8<<<NE,256,0,stream>>>(Xp, gsrc_e, off_e, cnt_e, nullptr, Ye);   // Xe
  k_avg8<<<NV,256,0,stream>>>(Ye, gsrc_v, off_v, cnt_v, Xp, Xp);        // Xt += hspd

  // ---- layer 2: output conv (C=40, scores fused) ----
  k_gemm2<<<(NV+15)/16,256,0,stream>>>(Xp, Wo, bo, avo, Xp2, rs1_v);
  k_agg1<true><<<NE,256,0,stream>>>(Xp2, gsrc_e, off_e, rs1_v, Ye2, aeo, rs1_e);
  k_agg1<false><<<NV,256,0,stream>>>(Ye2, gsrc_v, off_v, rs1_e, out, nullptr, nullptr);
}